// Round 1
// baseline (544.947 us; speedup 1.0000x reference)
//
#include <hip/hip_runtime.h>

#define HH 128
#define WW 128

// ---------------------------------------------------------------------------
// Prep 1: transpose conv_w [co][ci][tap] -> wt [ci][tap][co]  (36864 floats)
// ---------------------------------------------------------------------------
__global__ __launch_bounds__(256) void prep_wt(const float* __restrict__ conv_w,
                                               float* __restrict__ wt) {
  int tid = blockIdx.x * 256 + threadIdx.x;
  if (tid >= 64 * 9 * 64) return;
  int co  = tid & 63;
  int tap = (tid >> 6) % 9;
  int ci  = tid / 576;
  wt[tid] = conv_w[(co * 64 + ci) * 9 + tap];
}

// ---------------------------------------------------------------------------
// Prep 2: the grouped conv of a spatially-constant input collapses to a
// 9-case (boundary) table per (b, co):
//   ext[b][co][cy][cx] = conv_b[co] + extra_b[co]
//                      + sum_f ein[b, co*3+f] * sum_{valid ky in cy, kx in cx} w
// cases: 0 = at 0-edge (taps {1,2}), 1 = interior (all), 2 = at (N-1)-edge ({0,1})
// ---------------------------------------------------------------------------
__global__ __launch_bounds__(256) void prep_ext(const float* __restrict__ extra_in,
                                                const float* __restrict__ extra_w,
                                                const float* __restrict__ conv_b,
                                                const float* __restrict__ extra_b,
                                                float* __restrict__ ext) {
  int t = blockIdx.x * 256 + threadIdx.x;
  if (t >= 32 * 64) return;
  int b = t >> 6, co = t & 63;
  float base = conv_b[co] + extra_b[co];
  float acc[3][3];
#pragma unroll
  for (int i = 0; i < 3; ++i)
#pragma unroll
    for (int j = 0; j < 3; ++j) acc[i][j] = 0.f;

#pragma unroll
  for (int f = 0; f < 3; ++f) {
    float e = extra_in[b * 192 + co * 3 + f];
    const float* w = extra_w + (co * 3 + f) * 9;
    float rs[3][3];  // rs[ky][cx] = row sum of kx subset for column-case cx
#pragma unroll
    for (int ky = 0; ky < 3; ++ky) {
      float w0 = w[ky * 3 + 0], w1 = w[ky * 3 + 1], w2 = w[ky * 3 + 2];
      rs[ky][0] = w1 + w2;       // x == 0      -> kx in {1,2}
      rs[ky][1] = w0 + w1 + w2;  // interior    -> all
      rs[ky][2] = w0 + w1;       // x == W-1    -> kx in {0,1}
    }
#pragma unroll
    for (int cx = 0; cx < 3; ++cx) {
      acc[0][cx] += e * (rs[1][cx] + rs[2][cx]);             // y == 0
      acc[1][cx] += e * (rs[0][cx] + rs[1][cx] + rs[2][cx]); // interior
      acc[2][cx] += e * (rs[0][cx] + rs[1][cx]);             // y == H-1
    }
  }
#pragma unroll
  for (int cy = 0; cy < 3; ++cy)
#pragma unroll
    for (int cx = 0; cx < 3; ++cx)
      ext[t * 9 + cy * 3 + cx] = base + acc[cy][cx];
}

// ---------------------------------------------------------------------------
// Main conv: block = (batch b, 16x16 spatial tile), all 64 couts.
// thread = 4 couts x (4x4 pixel block). CIN staged in LDS in chunks of 8.
// ---------------------------------------------------------------------------
__global__ __launch_bounds__(256) void conv_main(const float* __restrict__ x,
                                                 const float* __restrict__ wt,
                                                 const float* __restrict__ ext,
                                                 float* __restrict__ out) {
  const int b  = blockIdx.y;
  const int ty = blockIdx.x >> 3, tx = blockIdx.x & 7;
  const int y0 = ty * 16, x0 = tx * 16;
  const int tid = threadIdx.x;
  const int bx = tid & 3;          // pixel-block x (4 cols)
  const int by = (tid >> 2) & 3;   // pixel-block y (4 rows)
  const int cot = tid >> 4;        // 0..15, co base = cot*4
  const int cobase = cot * 4;

  __shared__ float s_in[8][18][20];  // [ci][row][col], col stride 20 -> 16B-aligned float4

  float acc[4][16];
#pragma unroll
  for (int j = 0; j < 4; ++j)
#pragma unroll
    for (int p = 0; p < 16; ++p) acc[j][p] = 0.f;

  const float* xb = x + (size_t)b * (64 * HH * WW);

  for (int cc = 0; cc < 8; ++cc) {  // ci chunks of 8
    __syncthreads();
    // ---- stage input chunk [8][18][18] (zero-padded at image border) ----
#pragma unroll
    for (int it = 0; it < 11; ++it) {
      int idx = tid + it * 256;
      if (idx < 8 * 18 * 18) {
        int ci  = idx / 324;
        int rem = idx - ci * 324;
        int r   = rem / 18;
        int c   = rem - r * 18;
        int gy = y0 - 1 + r, gx = x0 - 1 + c;
        float v = 0.f;
        if (gy >= 0 && gy < HH && gx >= 0 && gx < WW)
          v = xb[((cc * 8 + ci) * HH + gy) * WW + gx];
        s_in[ci][r][c] = v;
      }
    }
    __syncthreads();

    for (int ci = 0; ci < 8; ++ci) {
      // 6x6 input patch for this thread's 4x4 pixels
      float p[6][6];
#pragma unroll
      for (int r = 0; r < 6; ++r) {
        const float* row = &s_in[ci][by * 4 + r][bx * 4];
        float4 v4 = *(const float4*)row;
        float2 v2 = *(const float2*)(row + 4);
        p[r][0] = v4.x; p[r][1] = v4.y; p[r][2] = v4.z; p[r][3] = v4.w;
        p[r][4] = v2.x; p[r][5] = v2.y;
      }
      const float* wrow = wt + (size_t)(cc * 8 + ci) * 9 * 64 + cobase;
#pragma unroll
      for (int tap = 0; tap < 9; ++tap) {
        float4 w4 = *(const float4*)(wrow + tap * 64);
        const int ky = tap / 3, kx = tap - ky * 3;
#pragma unroll
        for (int py = 0; py < 4; ++py) {
#pragma unroll
          for (int px = 0; px < 4; ++px) {
            float iv = p[py + ky][px + kx];
            acc[0][py * 4 + px] = fmaf(w4.x, iv, acc[0][py * 4 + px]);
            acc[1][py * 4 + px] = fmaf(w4.y, iv, acc[1][py * 4 + px]);
            acc[2][py * 4 + px] = fmaf(w4.z, iv, acc[2][py * 4 + px]);
            acc[3][py * 4 + px] = fmaf(w4.w, iv, acc[3][py * 4 + px]);
          }
        }
      }
    }
  }

  // ---- epilogue: add boundary-case extra table, write float4 ----
  const float* extb = ext + (size_t)(b * 64 + cobase) * 9;
#pragma unroll
  for (int j = 0; j < 4; ++j) {
#pragma unroll
    for (int py = 0; py < 4; ++py) {
      int y  = y0 + by * 4 + py;
      int cy = (y == 0) ? 0 : ((y == HH - 1) ? 2 : 1);
      float o[4];
#pragma unroll
      for (int px = 0; px < 4; ++px) {
        int xg = x0 + bx * 4 + px;
        int cx = (xg == 0) ? 0 : ((xg == WW - 1) ? 2 : 1);
        o[px] = acc[j][py * 4 + px] + extb[j * 9 + cy * 3 + cx];
      }
      float4 ov = make_float4(o[0], o[1], o[2], o[3]);
      *(float4*)&out[(((size_t)b * 64 + cobase + j) * HH + y) * WW + x0 + bx * 4] = ov;
    }
  }
}

extern "C" void kernel_launch(void* const* d_in, const int* in_sizes, int n_in,
                              void* d_out, int out_size, void* d_ws, size_t ws_size,
                              hipStream_t stream) {
  const float* x        = (const float*)d_in[0];
  const float* extra_in = (const float*)d_in[1];
  const float* conv_w   = (const float*)d_in[2];
  const float* conv_b   = (const float*)d_in[3];
  const float* extra_w  = (const float*)d_in[4];
  const float* extra_b  = (const float*)d_in[5];
  float* out = (float*)d_out;

  float* wt  = (float*)d_ws;          // 36864 floats
  float* ext = wt + 64 * 9 * 64;      // 2048 * 9 floats

  hipLaunchKernelGGL(prep_wt,  dim3(144), dim3(256), 0, stream, conv_w, wt);
  hipLaunchKernelGGL(prep_ext, dim3(8),   dim3(256), 0, stream,
                     extra_in, extra_w, conv_b, extra_b, ext);
  hipLaunchKernelGGL(conv_main, dim3(64, 32), dim3(256), 0, stream, x, wt, ext, out);
}

// Round 2
// 105.860 us; speedup vs baseline: 5.1478x; 5.1478x over previous
//
#include <hip/hip_runtime.h>

#define HH 128
#define WW 128

typedef __bf16 bf16x8 __attribute__((ext_vector_type(8)));
typedef float f32x4 __attribute__((ext_vector_type(4)));

static __device__ __forceinline__ unsigned short f2bf(float f) {
  unsigned int u = __float_as_uint(f);
  u = (u + 0x7FFFu + ((u >> 16) & 1u)) >> 16;  // RNE
  return (unsigned short)u;
}

// ---------------------------------------------------------------------------
// Prep 1: pack conv_w [co][ci][tap] into MFMA A-fragment order (bf16):
//   wfrag[f = h*9+tap][cotile][lane][i] = conv_w[cotile*16 + lane%16]
//                                               [h*32 + (lane/16)*8 + i][tap]
// 18 * 4 * 64 * 8 = 36864 bf16 elements.
// ---------------------------------------------------------------------------
__global__ __launch_bounds__(256) void prep_wfrag(const float* __restrict__ conv_w,
                                                  unsigned short* __restrict__ wfrag) {
  int tid = blockIdx.x * 256 + threadIdx.x;
  if (tid >= 18 * 2048) return;
  int i    = tid & 7;
  int lane = (tid >> 3) & 63;
  int cot  = (tid >> 9) & 3;
  int f    = tid >> 11;           // 0..17
  int h    = f / 9;               // ci half
  int tap  = f - h * 9;
  int co   = cot * 16 + (lane & 15);
  int ci   = h * 32 + (lane >> 4) * 8 + i;
  wfrag[tid] = f2bf(conv_w[(co * 64 + ci) * 9 + tap]);
}

// ---------------------------------------------------------------------------
// Prep 2: grouped conv of spatially-constant input -> 9-case boundary table
//   ext[b][co][cy][cx]  (includes conv_b + extra_b)
// ---------------------------------------------------------------------------
__global__ __launch_bounds__(256) void prep_ext(const float* __restrict__ extra_in,
                                                const float* __restrict__ extra_w,
                                                const float* __restrict__ conv_b,
                                                const float* __restrict__ extra_b,
                                                float* __restrict__ ext) {
  int t = blockIdx.x * 256 + threadIdx.x;
  if (t >= 32 * 64) return;
  int b = t >> 6, co = t & 63;
  float base = conv_b[co] + extra_b[co];
  float acc[3][3];
#pragma unroll
  for (int i = 0; i < 3; ++i)
#pragma unroll
    for (int j = 0; j < 3; ++j) acc[i][j] = 0.f;

#pragma unroll
  for (int f = 0; f < 3; ++f) {
    float e = extra_in[b * 192 + co * 3 + f];
    const float* w = extra_w + (co * 3 + f) * 9;
    float rs[3][3];
#pragma unroll
    for (int ky = 0; ky < 3; ++ky) {
      float w0 = w[ky * 3 + 0], w1 = w[ky * 3 + 1], w2 = w[ky * 3 + 2];
      rs[ky][0] = w1 + w2;
      rs[ky][1] = w0 + w1 + w2;
      rs[ky][2] = w0 + w1;
    }
#pragma unroll
    for (int cx = 0; cx < 3; ++cx) {
      acc[0][cx] += e * (rs[1][cx] + rs[2][cx]);
      acc[1][cx] += e * (rs[0][cx] + rs[1][cx] + rs[2][cx]);
      acc[2][cx] += e * (rs[0][cx] + rs[1][cx]);
    }
  }
#pragma unroll
  for (int cy = 0; cy < 3; ++cy)
#pragma unroll
    for (int cx = 0; cx < 3; ++cx)
      ext[t * 9 + cy * 3 + cx] = base + acc[cy][cx];
}

// ---------------------------------------------------------------------------
// Main: implicit-GEMM conv via mfma_f32_16x16x32_bf16.
// Block = (batch, 4 rows x 64 cols), 256 thr = 4 waves, wave = 1 output row.
// LDS: channel-last tile s[6 rows][68 cols][64 ci] bf16, XOR-swizzled.
// Wave computes D[64 co][64 pix]: 4 cotiles x 4 pixtiles, K = 9 taps x 64 ci.
// ---------------------------------------------------------------------------
__global__ __launch_bounds__(256, 2) void conv_mfma(const float* __restrict__ x,
                                                    const unsigned short* __restrict__ wfrag,
                                                    const float* __restrict__ ext,
                                                    float* __restrict__ out) {
  const int b  = blockIdx.z;
  const int y0 = blockIdx.y * 4;
  const int x0 = blockIdx.x * 64;
  const int tid  = threadIdx.x;
  const int lane = tid & 63;
  const int wv   = tid >> 6;  // wave id = output row offset

  __shared__ __align__(16) unsigned char sbuf[6 * 68 * 128];  // [r][c][64ci] bf16

  const float* xb = x + (size_t)b * 64 * HH * WW;

  // ---- stage 6x66x64 halo tile, channel-last bf16, swizzled ----
  // pack q -> (c = q%66, cig = (q/66)%8, r = q/528); thread packs 8 ci.
  for (int it = 0; it < 13; ++it) {
    int q = tid + it * 256;
    if (q < 3168) {
      int c   = q % 66;
      int t2  = q / 66;
      int cig = t2 & 7;
      int r   = t2 >> 3;
      int y_in = y0 - 1 + r;
      int x_in = x0 - 1 + c;
      bool inb = ((unsigned)y_in < 128u) & ((unsigned)x_in < 128u);
      const float* src = xb + (size_t)(cig * 8) * (HH * WW) + y_in * WW + x_in;
      unsigned int pk[4] = {0u, 0u, 0u, 0u};
      if (inb) {
#pragma unroll
        for (int j = 0; j < 8; ++j) {
          unsigned short us = f2bf(src[j * (HH * WW)]);
          pk[j >> 1] |= ((unsigned int)us) << ((j & 1) * 16);
        }
      }
      int byte = (r * 68 + c) * 128 + cig * 16;
      byte ^= (c & 7) << 4;
      *(uint4*)(sbuf + byte) = make_uint4(pk[0], pk[1], pk[2], pk[3]);
    }
  }
  __syncthreads();

  f32x4 acc[4][4];
#pragma unroll
  for (int i = 0; i < 4; ++i)
#pragma unroll
    for (int j = 0; j < 4; ++j) acc[i][j] = (f32x4){0.f, 0.f, 0.f, 0.f};

  const int pix = lane & 15;
  const int g   = lane >> 4;

  for (int h = 0; h < 2; ++h) {
#pragma unroll 1
    for (int tap = 0; tap < 9; ++tap) {
      const int ky = tap / 3, kx = tap - ky * 3;
      // A-fragments: weights from global (L1/L2-hot)
      const unsigned short* wbase = wfrag + (size_t)(h * 9 + tap) * 2048 + lane * 8;
      bf16x8 af[4];
#pragma unroll
      for (int cot = 0; cot < 4; ++cot)
        af[cot] = *(const bf16x8*)(wbase + cot * 512);
      // B-fragments: pixels from LDS
      bf16x8 pf[4];
      const int r = wv + ky;
#pragma unroll
      for (int m = 0; m < 4; ++m) {
        int c = m * 16 + pix + kx;
        int byte = (r * 68 + c) * 128 + h * 64 + g * 16;
        byte ^= (c & 7) << 4;
        pf[m] = *(const bf16x8*)(sbuf + byte);
      }
#pragma unroll
      for (int cot = 0; cot < 4; ++cot)
#pragma unroll
        for (int m = 0; m < 4; ++m)
          acc[cot][m] = __builtin_amdgcn_mfma_f32_16x16x32_bf16(af[cot], pf[m],
                                                                acc[cot][m], 0, 0, 0);
    }
  }

  // ---- epilogue: add boundary-case table, coalesced stores ----
  const int y  = y0 + wv;
  const int cy = (y == 0) ? 0 : ((y == HH - 1) ? 2 : 1);
  const float* extb = ext + (size_t)b * 64 * 9;
#pragma unroll
  for (int cot = 0; cot < 4; ++cot) {
#pragma unroll
    for (int m = 0; m < 4; ++m) {
      int xg = x0 + m * 16 + pix;
      int cx = (xg == 0) ? 0 : ((xg == WW - 1) ? 2 : 1);
#pragma unroll
      for (int j = 0; j < 4; ++j) {
        int co = cot * 16 + g * 4 + j;
        float v = acc[cot][m][j] + extb[co * 9 + cy * 3 + cx];
        out[(((size_t)b * 64 + co) * HH + y) * WW + xg] = v;
      }
    }
  }
}

extern "C" void kernel_launch(void* const* d_in, const int* in_sizes, int n_in,
                              void* d_out, int out_size, void* d_ws, size_t ws_size,
                              hipStream_t stream) {
  const float* x        = (const float*)d_in[0];
  const float* extra_in = (const float*)d_in[1];
  const float* conv_w   = (const float*)d_in[2];
  const float* conv_b   = (const float*)d_in[3];
  const float* extra_w  = (const float*)d_in[4];
  const float* extra_b  = (const float*)d_in[5];
  float* out = (float*)d_out;

  unsigned short* wfrag = (unsigned short*)d_ws;              // 73728 B
  float* ext = (float*)((char*)d_ws + 73728);                 // 73728 B

  hipLaunchKernelGGL(prep_wfrag, dim3(144), dim3(256), 0, stream, conv_w, wfrag);
  hipLaunchKernelGGL(prep_ext,   dim3(8),   dim3(256), 0, stream,
                     extra_in, extra_w, conv_b, extra_b, ext);
  hipLaunchKernelGGL(conv_mfma, dim3(2, 32, 32), dim3(256), 0, stream,
                     x, wfrag, ext, out);
}

// Round 3
// 95.552 us; speedup vs baseline: 5.7031x; 1.1079x over previous
//
#include <hip/hip_runtime.h>

#define HH 128
#define WW 128

typedef __bf16 bf16x8 __attribute__((ext_vector_type(8)));
typedef float f32x4 __attribute__((ext_vector_type(4)));

static __device__ __forceinline__ unsigned short f2bf(float f) {
  unsigned int u = __float_as_uint(f);
  u = (u + 0x7FFFu + ((u >> 16) & 1u)) >> 16;  // RNE
  return (unsigned short)u;
}

// ---------------------------------------------------------------------------
// Prep 1: pack conv_w [co][ci][tap] into MFMA A-fragment order (bf16):
//   wfrag[f = h*9+tap][cotile][lane][i] = conv_w[cotile*16 + lane%16]
//                                               [h*32 + (lane/16)*8 + i][tap]
// ---------------------------------------------------------------------------
__global__ __launch_bounds__(256) void prep_wfrag(const float* __restrict__ conv_w,
                                                  unsigned short* __restrict__ wfrag) {
  int tid = blockIdx.x * 256 + threadIdx.x;
  if (tid >= 18 * 2048) return;
  int i    = tid & 7;
  int lane = (tid >> 3) & 63;
  int cot  = (tid >> 9) & 3;
  int f    = tid >> 11;           // 0..17
  int h    = f / 9;               // ci half
  int tap  = f - h * 9;
  int co   = cot * 16 + (lane & 15);
  int ci   = h * 32 + (lane >> 4) * 8 + i;
  wfrag[tid] = f2bf(conv_w[(co * 64 + ci) * 9 + tap]);
}

// ---------------------------------------------------------------------------
// Prep 2: grouped conv of spatially-constant input -> 9-case boundary table
//   ext[b][co][cy][cx]  (includes conv_b + extra_b)
// ---------------------------------------------------------------------------
__global__ __launch_bounds__(256) void prep_ext(const float* __restrict__ extra_in,
                                                const float* __restrict__ extra_w,
                                                const float* __restrict__ conv_b,
                                                const float* __restrict__ extra_b,
                                                float* __restrict__ ext) {
  int t = blockIdx.x * 256 + threadIdx.x;
  if (t >= 32 * 64) return;
  int b = t >> 6, co = t & 63;
  float base = conv_b[co] + extra_b[co];
  float acc[3][3];
#pragma unroll
  for (int i = 0; i < 3; ++i)
#pragma unroll
    for (int j = 0; j < 3; ++j) acc[i][j] = 0.f;

#pragma unroll
  for (int f = 0; f < 3; ++f) {
    float e = extra_in[b * 192 + co * 3 + f];
    const float* w = extra_w + (co * 3 + f) * 9;
    float rs[3][3];
#pragma unroll
    for (int ky = 0; ky < 3; ++ky) {
      float w0 = w[ky * 3 + 0], w1 = w[ky * 3 + 1], w2 = w[ky * 3 + 2];
      rs[ky][0] = w1 + w2;
      rs[ky][1] = w0 + w1 + w2;
      rs[ky][2] = w0 + w1;
    }
#pragma unroll
    for (int cx = 0; cx < 3; ++cx) {
      acc[0][cx] += e * (rs[1][cx] + rs[2][cx]);
      acc[1][cx] += e * (rs[0][cx] + rs[1][cx] + rs[2][cx]);
      acc[2][cx] += e * (rs[0][cx] + rs[1][cx]);
    }
  }
#pragma unroll
  for (int cy = 0; cy < 3; ++cy)
#pragma unroll
    for (int cx = 0; cx < 3; ++cx)
      ext[t * 9 + cy * 3 + cx] = base + acc[cy][cx];
}

// ---------------------------------------------------------------------------
// Main: implicit-GEMM conv via mfma_f32_16x16x32_bf16.
// Block = (batch, 4 rows x 64 cols), 256 thr = 4 waves, wave = 1 output row.
// ci split in two halves of 32, staged one at a time:
//   LDS s[6 rows][68 cols][32 ci] bf16 = 25.5 KB  -> 6 blocks/CU.
// Swizzle: byte ^= ((c ^ (c>>2)) & 3) << 4  (8 distinct 16B quads per 8 c's
// -> 2-way lane aliasing on both ds_write_b128 and ds_read_b128 = free).
// ---------------------------------------------------------------------------
__global__ __launch_bounds__(256) void conv_mfma(const float* __restrict__ x,
                                                 const unsigned short* __restrict__ wfrag,
                                                 const float* __restrict__ ext,
                                                 float* __restrict__ out) {
  const int b  = blockIdx.z;
  const int y0 = blockIdx.y * 4;
  const int x0 = blockIdx.x * 64;
  const int tid  = threadIdx.x;
  const int lane = tid & 63;
  const int wv   = tid >> 6;  // wave id = output row offset

  __shared__ __align__(16) unsigned char sbuf[6 * 68 * 64];  // [r][c][32ci] bf16

  const float* xb = x + (size_t)b * 64 * HH * WW;

  f32x4 acc[4][4];
#pragma unroll
  for (int i = 0; i < 4; ++i)
#pragma unroll
    for (int j = 0; j < 4; ++j) acc[i][j] = (f32x4){0.f, 0.f, 0.f, 0.f};

  const int pix = lane & 15;
  const int g   = lane >> 4;

  for (int h = 0; h < 2; ++h) {
    __syncthreads();  // previous half's compute done before overwrite
    // ---- stage 6x66x32 halo half-tile, channel-last bf16, swizzled ----
    // q -> (c = q%66, cig = (q/66)%4, r = q/264); thread packs 8 ci.
#pragma unroll
    for (int it = 0; it < 7; ++it) {
      int q = tid + it * 256;
      if (q < 1584) {
        int c   = q % 66;
        int t2  = q / 66;
        int cig = t2 & 3;
        int r   = t2 >> 2;
        int y_in = y0 - 1 + r;
        int x_in = x0 - 1 + c;
        bool inb = ((unsigned)y_in < 128u) & ((unsigned)x_in < 128u);
        const float* src = xb + (size_t)(h * 32 + cig * 8) * (HH * WW) + y_in * WW + x_in;
        unsigned int pk[4] = {0u, 0u, 0u, 0u};
        if (inb) {
#pragma unroll
          for (int j = 0; j < 8; ++j) {
            unsigned short us = f2bf(src[j * (HH * WW)]);
            pk[j >> 1] |= ((unsigned int)us) << ((j & 1) * 16);
          }
        }
        int byte = (r * 68 + c) * 64 + cig * 16;
        byte ^= ((c ^ (c >> 2)) & 3) << 4;
        *(uint4*)(sbuf + byte) = make_uint4(pk[0], pk[1], pk[2], pk[3]);
      }
    }
    __syncthreads();

#pragma unroll 1
    for (int tap = 0; tap < 9; ++tap) {
      const int ky = tap / 3, kx = tap - ky * 3;
      // A-fragments: weights from global (L1/L2-hot)
      const unsigned short* wbase = wfrag + (size_t)(h * 9 + tap) * 2048 + lane * 8;
      bf16x8 af[4];
#pragma unroll
      for (int cot = 0; cot < 4; ++cot)
        af[cot] = *(const bf16x8*)(wbase + cot * 512);
      // B-fragments: pixels from LDS
      bf16x8 pf[4];
      const int r = wv + ky;
#pragma unroll
      for (int m = 0; m < 4; ++m) {
        int c = m * 16 + pix + kx;
        int byte = (r * 68 + c) * 64 + g * 16;
        byte ^= ((c ^ (c >> 2)) & 3) << 4;
        pf[m] = *(const bf16x8*)(sbuf + byte);
      }
#pragma unroll
      for (int cot = 0; cot < 4; ++cot)
#pragma unroll
        for (int m = 0; m < 4; ++m)
          acc[cot][m] = __builtin_amdgcn_mfma_f32_16x16x32_bf16(af[cot], pf[m],
                                                                acc[cot][m], 0, 0, 0);
    }
  }

  // ---- epilogue: add boundary-case table, coalesced stores ----
  const int y  = y0 + wv;
  const int cy = (y == 0) ? 0 : ((y == HH - 1) ? 2 : 1);
  const float* extb = ext + (size_t)b * 64 * 9;
#pragma unroll
  for (int cot = 0; cot < 4; ++cot) {
#pragma unroll
    for (int m = 0; m < 4; ++m) {
      int xg = x0 + m * 16 + pix;
      int cx = (xg == 0) ? 0 : ((xg == WW - 1) ? 2 : 1);
#pragma unroll
      for (int j = 0; j < 4; ++j) {
        int co = cot * 16 + g * 4 + j;
        float v = acc[cot][m][j] + extb[co * 9 + cy * 3 + cx];
        out[(((size_t)b * 64 + co) * HH + y) * WW + xg] = v;
      }
    }
  }
}

extern "C" void kernel_launch(void* const* d_in, const int* in_sizes, int n_in,
                              void* d_out, int out_size, void* d_ws, size_t ws_size,
                              hipStream_t stream) {
  const float* x        = (const float*)d_in[0];
  const float* extra_in = (const float*)d_in[1];
  const float* conv_w   = (const float*)d_in[2];
  const float* conv_b   = (const float*)d_in[3];
  const float* extra_w  = (const float*)d_in[4];
  const float* extra_b  = (const float*)d_in[5];
  float* out = (float*)d_out;

  unsigned short* wfrag = (unsigned short*)d_ws;              // 73728 B
  float* ext = (float*)((char*)d_ws + 73728);                 // 73728 B

  hipLaunchKernelGGL(prep_wfrag, dim3(144), dim3(256), 0, stream, conv_w, wfrag);
  hipLaunchKernelGGL(prep_ext,   dim3(8),   dim3(256), 0, stream,
                     extra_in, extra_w, conv_b, extra_b, ext);
  hipLaunchKernelGGL(conv_mfma, dim3(2, 32, 32), dim3(256), 0, stream,
                     x, wfrag, ext, out);
}